// Round 9
// baseline (107.869 us; speedup 1.0000x reference)
//
#include <hip/hip_runtime.h>
#include <hip/hip_fp16.h>
#include <math.h>

#define DEG 32
#define NHO 64   // HEADS*OUT_F = 4*16
#define NPB 16   // nodes per block (4 waves x 4 slots)

typedef short    frag8 __attribute__((ext_vector_type(8)));   // 8 bf16 = 4 VGPRs
typedef float    f32x4 __attribute__((ext_vector_type(4)));
typedef _Float16 h2    __attribute__((ext_vector_type(2)));

__device__ __forceinline__ h2 as_h2(unsigned u) {
    union { unsigned u; h2 h; } x; x.u = u; return x.h;
}
__device__ __forceinline__ unsigned h2_add(unsigned a, unsigned b) {
    h2 r = as_h2(a) + as_h2(b);                 // v_pk_add_f16
    union { h2 h; unsigned u; } x; x.h = r; return x.u;
}

// DPP butterfly add within quads (4 lanes): xor1=0xB1, xor2=0x4E.
template <int CTRL>
__device__ __forceinline__ float dpp_add(float v) {
    int t = __builtin_amdgcn_update_dpp(0, __float_as_int(v), CTRL, 0xF, 0xF, true);
    return v + __int_as_float(t);
}

__device__ __forceinline__ unsigned bf16_rne(float f) {
    unsigned u = __float_as_uint(f);
    return (u + 0x7fffu + ((u >> 16) & 1u)) >> 16;
}

// ---------------------------------------------------------------------------
// MFMA projection: C[128][N] = W'[128][64] x Q[64][N]; rows 0-63 -> Pqh,
// rows 64-127 -> Pkh, both f16 [N][64] (128 B rows).
// ---------------------------------------------------------------------------
__global__ __launch_bounds__(256) void proj_mfma_kernel(
    const float* __restrict__ Q,
    const float* __restrict__ Wq,
    const float* __restrict__ Wk,
    unsigned short* __restrict__ Pqh,
    unsigned short* __restrict__ Pkh,
    int N)
{
    __shared__ unsigned qlds[64 * 33];    // [n][k-pair] packed bf16
    __shared__ unsigned wlds[128 * 33];   // [l][k-pair]

    int t  = threadIdx.x;
    int n0 = blockIdx.x * 64;

    {
        int l    = t >> 1;
        int half = t & 1;
        const float* wr = (l < 64 ? Wq + (size_t)l * 64
                                  : Wk + (size_t)(l - 64) * 64) + half * 32;
#pragma unroll
        for (int r = 0; r < 16; r++) {
            float f0 = wr[2 * r], f1 = wr[2 * r + 1];
            wlds[l * 33 + half * 16 + r] = bf16_rne(f0) | (bf16_rne(f1) << 16);
        }
    }
    {
        int n  = t & 63;
        int gn = n0 + n;
        bool act = (gn < N);
#pragma unroll
        for (int r = 0; r < 8; r++) {
            int dp = (t >> 6) * 8 + r;
            int k  = dp * 2;
            float f0 = act ? Q[(size_t)k * N + gn] : 0.f;
            float f1 = act ? Q[(size_t)(k + 1) * N + gn] : 0.f;
            qlds[n * 33 + dp] = bf16_rne(f0) | (bf16_rne(f1) << 16);
        }
    }
    __syncthreads();

    int lane = t & 63;
    int w    = t >> 6;
    int li   = lane & 15;
    int quad = lane >> 4;

    f32x4 acc[8];
#pragma unroll
    for (int ot = 0; ot < 8; ot++) acc[ot] = (f32x4){0.f, 0.f, 0.f, 0.f};

#pragma unroll
    for (int ks = 0; ks < 2; ks++) {
        union { unsigned u[4]; frag8 f; } A;
        int abase = (w * 16 + li) * 33 + ks * 16 + quad * 4;
#pragma unroll
        for (int c = 0; c < 4; c++) A.u[c] = qlds[abase + c];
#pragma unroll
        for (int ot = 0; ot < 8; ot++) {
            union { unsigned u[4]; frag8 f; } B;
            int bbase = (ot * 16 + li) * 33 + ks * 16 + quad * 4;
#pragma unroll
            for (int c = 0; c < 4; c++) B.u[c] = wlds[bbase + c];
            acc[ot] = __builtin_amdgcn_mfma_f32_16x16x32_bf16(A.f, B.f, acc[ot],
                                                              0, 0, 0);
        }
    }

#pragma unroll
    for (int ot = 0; ot < 8; ot++) {
#pragma unroll
        for (int r = 0; r < 4; r++) {
            int node = n0 + w * 16 + quad * 4 + r;
            if (node < N) {
                unsigned short v = __half_as_ushort(__float2half(acc[ot][r]));
                if (ot < 4)
                    Pqh[(size_t)node * NHO + ot * 16 + li] = v;
                else
                    Pkh[(size_t)node * NHO + (ot - 4) * 16 + li] = v;
            }
        }
    }
}

// ---------------------------------------------------------------------------
// GAT, slot-per-node. Lane l: slot = l>>4 owns node nbase+slot, sl = l&15
// covers ho-quad {4sl..4sl+3}. 32 edge-iterations, one edge per slot per
// iteration: gather uint2 = 4 f16 (16 lanes = one full 128 B row per slot).
// Logit: c1q + dot2(c1,kv) + dot2(c2,|q+kv|) (packed f16), quad DPP reduce.
// Softmax state (s, a0..a3) is quad-uniform -> no cross-lane combine.
// ---------------------------------------------------------------------------
__global__ __launch_bounds__(256) void gat_kernel(
    const int*            __restrict__ adj,   // [N][DEG]
    const unsigned short* __restrict__ Pqh,   // [N][64] f16
    const unsigned short* __restrict__ Pkh,   // [N][64] f16
    const float*          __restrict__ aw,    // [64]
    float*                __restrict__ out,   // [64][N]
    int N)
{
    __shared__ float tile[NHO][NPB + 1];

    int l    = threadIdx.x & 63;
    int wv   = threadIdx.x >> 6;
    int sl   = l & 15;
    int slot = l >> 4;

    const uint2* Pk64 = (const uint2*)Pkh;   // 16 uint2 per 128 B row
    const uint2* Pq64 = (const uint2*)Pqh;

    float4 awq = *(const float4*)(aw + 4 * sl);
    const float L2E = 1.44269504f;
    float c10 = 0.505f * L2E * awq.x, c20 = 0.495f * L2E * awq.x;
    float c11 = 0.505f * L2E * awq.y, c21 = 0.495f * L2E * awq.y;
    float c12 = 0.505f * L2E * awq.z, c22 = 0.495f * L2E * awq.z;
    float c13 = 0.505f * L2E * awq.w, c23 = 0.495f * L2E * awq.w;
    h2 c1a = {(_Float16)c10, (_Float16)c11};
    h2 c1b = {(_Float16)c12, (_Float16)c13};
    h2 c2a = {(_Float16)c20, (_Float16)c21};
    h2 c2b = {(_Float16)c22, (_Float16)c23};

    int n = blockIdx.x * NPB + wv * 4 + slot;   // this slot's node
    bool act = (n < N);
    int nc_ = act ? n : 0;

    uint2 qraw = Pq64[(size_t)nc_ * 16 + sl];
    int2  av   = ((const int2*)adj)[(size_t)nc_ * 16 + sl];  // edges 2sl,2sl+1

    // c1q = sum over this lane's 4 ho of c1*qp (f32 accumulate)
    float c1q = __builtin_amdgcn_fdot2(c1a, as_h2(qraw.x),
                 __builtin_amdgcn_fdot2(c1b, as_h2(qraw.y), 0.f, false), false);

    float s = 0.f, a0 = 0.f, a1 = 0.f, a2 = 0.f, a3 = 0.f;

#pragma unroll
    for (int ch = 0; ch < 4; ch++) {
        int   jv[8];
        uint2 kvr[8];
#pragma unroll
        for (int t8 = 0; t8 < 8; t8++) {
            int t = ch * 8 + t8;                       // edge index 0..31
            int addr = (slot * 16 + (t >> 1)) * 4;     // source lane in slot
            int j = __builtin_amdgcn_ds_bpermute(addr, (t & 1) ? av.y : av.x);
            jv[t8] = j;
            kvr[t8] = Pk64[(size_t)(j < 0 ? 0 : j) * 16 + sl];
        }
#pragma unroll
        for (int t8 = 0; t8 < 8; t8++) {
            unsigned k01 = kvr[t8].x, k23 = kvr[t8].y;
            unsigned x01 = h2_add(k01, qraw.x) & 0x7fff7fffu;  // |qp+kv|
            unsigned x23 = h2_add(k23, qraw.y) & 0x7fff7fffu;
            float c = c1q;
            c = __builtin_amdgcn_fdot2(c1a, as_h2(k01), c, false);
            c = __builtin_amdgcn_fdot2(c1b, as_h2(k23), c, false);
            c = __builtin_amdgcn_fdot2(c2a, as_h2(x01), c, false);
            c = __builtin_amdgcn_fdot2(c2b, as_h2(x23), c, false);
            c = dpp_add<0xB1>(c);     // xor 1 (quad)
            c = dpp_add<0x4E>(c);     // xor 2 (quad) -> head logit
            float p = __builtin_amdgcn_exp2f(c);
            p = (jv[t8] >= 0) ? p : 0.f;
            s += p;
            h2 kva = as_h2(k01), kvb = as_h2(k23);
            a0 = fmaf(p, (float)kva[0], a0);
            a1 = fmaf(p, (float)kva[1], a1);
            a2 = fmaf(p, (float)kvb[0], a2);
            a3 = fmaf(p, (float)kvb[1], a3);
        }
    }

    if (act) {
        float rs = (s > 0.f) ? __builtin_amdgcn_rcpf(s) : 0.f;
        int col = wv * 4 + slot;
        tile[4 * sl + 0][col] = a0 * rs;
        tile[4 * sl + 1][col] = a1 * rs;
        tile[4 * sl + 2][col] = a2 * rs;
        tile[4 * sl + 3][col] = a3 * rs;
    }
    __syncthreads();

    // coalesced write-out: 64 rows x 16 cols, one float4 per thread
    int n0 = blockIdx.x * NPB;
    int lr = threadIdx.x >> 2;
    int c4 = threadIdx.x & 3;
    int nc = n0 + c4 * 4;
    float4 v = make_float4(tile[lr][c4 * 4 + 0], tile[lr][c4 * 4 + 1],
                           tile[lr][c4 * 4 + 2], tile[lr][c4 * 4 + 3]);
    if (nc + 3 < N) {
        *(float4*)(out + (size_t)lr * N + nc) = v;
    } else {
#pragma unroll
        for (int e = 0; e < 4; e++)
            if (nc + e < N) out[(size_t)lr * N + nc + e] = (&v.x)[e];
    }
}

extern "C" void kernel_launch(void* const* d_in, const int* in_sizes, int n_in,
                              void* d_out, int out_size, void* d_ws, size_t ws_size,
                              hipStream_t stream) {
    const int*   adj = (const int*)  d_in[0];
    const float* Q   = (const float*)d_in[1];
    const float* qw  = (const float*)d_in[2];
    const float* kw  = (const float*)d_in[3];
    const float* aw  = (const float*)d_in[4];
    float*       out = (float*)d_out;

    int N = in_sizes[0] / DEG;  // 50000

    unsigned short* Pqh = (unsigned short*)d_ws;     // [N][64] f16
    unsigned short* Pkh = Pqh + (size_t)N * NHO;     // [N][64] f16

    proj_mfma_kernel<<<(N + 63) / 64, 256, 0, stream>>>(Q, qw, kw, Pqh, Pkh, N);

    gat_kernel<<<(N + NPB - 1) / NPB, 256, 0, stream>>>(adj, Pqh, Pkh, aw, out, N);
}